// Round 8
// baseline (214.207 us; speedup 1.0000x reference)
//
#include <hip/hip_runtime.h>

#define DI __device__ __forceinline__

constexpr int B_ = 16;
constexpr int C_ = 512;
constexpr int W_ = 2048;
constexpr int C4 = 128;
constexpr int C2 = 256;
constexpr int Q_ = 1024;

typedef short bf16x8 __attribute__((ext_vector_type(8)));
typedef float f32x4 __attribute__((ext_vector_type(4)));

DI f32x4 MFMA(bf16x8 a, bf16x8 b, f32x4 c) {
  return __builtin_amdgcn_mfma_f32_16x16x32_bf16(a, b, c, 0, 0, 0);
}

DI unsigned short f2bf(float v) {
  union { float f; unsigned int i; } c; c.f = v;
  return (unsigned short)((c.i + 0x7FFFu + ((c.i >> 16) & 1u)) >> 16);
}

DI bf16x8 ldfrag(const unsigned short* p, int ld) {
  const int l = threadIdx.x & 63;
  return *(const bf16x8*)(p + (size_t)(l & 15) * ld + ((l >> 4) << 3));
}

// async 16B global->LDS; lds dest is wave-uniform base + lane*16
DI void gload16(const unsigned short* g, unsigned short* l) {
  __builtin_amdgcn_global_load_lds((const __attribute__((address_space(1))) void*)(g),
                                   (__attribute__((address_space(3))) void*)(l), 16, 0, 0);
}

// ---------------------------------------------------------------------------
// Prep 1: weights -> bf16.  [wf 64K][wg 64K][wh 128K][wa 128K]
// ---------------------------------------------------------------------------
__global__ __launch_bounds__(256)
void k_cvt(const float* __restrict__ wf, const float* __restrict__ wg,
           const float* __restrict__ wh, const float* __restrict__ wa,
           unsigned short* __restrict__ dst)
{
  const int i = blockIdx.x * 256 + threadIdx.x;
  float v;
  if (i < 65536)        v = wf[i];
  else if (i < 131072)  v = wg[i - 65536];
  else if (i < 262144)  v = wh[i - 131072];
  else                  v = wa[i - 262144];
  dst[i] = f2bf(v);
}

// ---------------------------------------------------------------------------
// Prep 2: xT[b][w][c] bf16 = transpose of x[b][c][w] f32.
// ---------------------------------------------------------------------------
__global__ __launch_bounds__(256)
void k_tx(const float* __restrict__ x, unsigned short* __restrict__ xT)
{
  __shared__ float tile[64][68];
  const int b = blockIdx.z, c0 = blockIdx.y * 64, w0 = blockIdx.x * 64;
  const int t = threadIdx.x;
  #pragma unroll
  for (int p = 0; p < 4; ++p) {
    const int r = p * 16 + (t >> 4);
    const float4 v = *(const float4*)&x[((size_t)(b * C_ + c0 + r)) * W_ + w0 + (t & 15) * 4];
    *(float4*)&tile[r][(t & 15) * 4] = v;
  }
  __syncthreads();
  const int w = t >> 2, ch = (t & 3) * 16;
  unsigned short o[16];
  #pragma unroll
  for (int j = 0; j < 16; ++j) o[j] = f2bf(tile[ch + j][w]);
  unsigned short* dst = &xT[((size_t)(b * W_ + w0 + w)) * C_ + c0 + ch];
  *(uint4*)&dst[0] = *(uint4*)&o[0];
  *(uint4*)&dst[8] = *(uint4*)&o[8];
}

// ---------------------------------------------------------------------------
// K1: m97-style LDS-staged GEMM. Tile 128(w) x 128(ch), BK=32, 4 waves 2x2.
// rt=0 -> fT (pooled,T), rt=1 -> gT (T), rt=2,3 -> h (pooled). grid (16,4,16)
// ---------------------------------------------------------------------------
__global__ __launch_bounds__(256)
void k_fgh(const unsigned short* __restrict__ xT, const unsigned short* __restrict__ wcat,
           const float* __restrict__ bfp, const float* __restrict__ bgp,
           const float* __restrict__ bhp,
           unsigned short* __restrict__ fT, unsigned short* __restrict__ gT,
           unsigned short* __restrict__ h)
{
  const int b = blockIdx.z, rt = blockIdx.y, w0 = blockIdx.x * 128;
  const int t = threadIdx.x, l = t & 63, wv = t >> 6;
  const int wr = wv >> 1, wc = wv & 1;

  __shared__ __align__(16) char smraw[33792];   // staging 32KB | epilogue 64x132 f32
  unsigned short* stg = (unsigned short*)smraw; // [buf][ab][4096]
  float (*eps)[132] = (float(*)[132])smraw;

  const unsigned short* Abase = xT + ((size_t)(b * W_ + w0)) * C_;
  const unsigned short* Bbase = wcat + (size_t)(rt * 128) * C_;

  const int wub = (t & 192) * 8;          // wave-uniform lds elem base per instr block
  const int r0s = t >> 2, kcs = (t & 3) * 8;

  auto STAGE = [&](int buf, int c0) {
    #pragma unroll
    for (int i = 0; i < 2; ++i) {
      const int row = i * 64 + r0s;
      gload16(Abase + (size_t)row * C_ + c0 + kcs, stg + (buf * 2 + 0) * 4096 + i * 2048 + wub);
      gload16(Bbase + (size_t)row * C_ + c0 + kcs, stg + (buf * 2 + 1) * 4096 + i * 2048 + wub);
    }
  };

  f32x4 acc[4][4];
  #pragma unroll
  for (int i = 0; i < 4; ++i)
    #pragma unroll
    for (int j = 0; j < 4; ++j) acc[i][j] = (f32x4){0.f, 0.f, 0.f, 0.f};

  STAGE(0, 0);
  for (int kt = 0; kt < 16; ++kt) {
    const int cur = kt & 1;
    __syncthreads();                       // drains vmcnt -> buf[cur] ready
    if (kt + 1 < 16) STAGE(cur ^ 1, (kt + 1) * 32);
    const unsigned short* As = stg + (cur * 2 + 0) * 4096;
    const unsigned short* Bs = stg + (cur * 2 + 1) * 4096;
    bf16x8 a[4], bb[4];
    #pragma unroll
    for (int i = 0; i < 4; ++i)
      a[i] = *(const bf16x8*)&As[(wr * 64 + i * 16 + (l & 15)) * 32 + ((l >> 4) << 3)];
    #pragma unroll
    for (int j = 0; j < 4; ++j)
      bb[j] = *(const bf16x8*)&Bs[(wc * 64 + j * 16 + (l & 15)) * 32 + ((l >> 4) << 3)];
    #pragma unroll
    for (int i = 0; i < 4; ++i)
      #pragma unroll
      for (int j = 0; j < 4; ++j)
        acc[i][j] = MFMA(a[i], bb[j], acc[i][j]);
  }
  __syncthreads();                          // staging arena -> epilogue overlay

  const int lr = l >> 4, lc = l & 15;

  if (rt == 1) {
    #pragma unroll
    for (int p = 0; p < 2; ++p) {
      if (p) __syncthreads();
      if (wr == p) {
        #pragma unroll
        for (int i = 0; i < 4; ++i)
          #pragma unroll
          for (int j = 0; j < 4; ++j)
            #pragma unroll
            for (int r = 0; r < 4; ++r)
              eps[i * 16 + lr * 4 + r][wc * 64 + j * 16 + lc] = acc[i][j][r];
      }
      __syncthreads();
      const int row = t >> 2, chunk = (t & 3) * 32;
      unsigned short o[32];
      #pragma unroll
      for (int j2 = 0; j2 < 32; ++j2) o[j2] = f2bf(eps[row][chunk + j2] + bgp[chunk + j2]);
      unsigned short* dst = &gT[((size_t)(b * W_ + w0 + p * 64 + row)) * C4 + chunk];
      #pragma unroll
      for (int u = 0; u < 4; ++u) *(uint4*)&dst[u * 8] = *(uint4*)&o[u * 8];
    }
  } else {
    #pragma unroll
    for (int i = 0; i < 4; ++i)
      #pragma unroll
      for (int j = 0; j < 4; ++j)
        #pragma unroll
        for (int jj = 0; jj < 2; ++jj)
          eps[wr * 32 + i * 8 + lr * 2 + jj][wc * 64 + j * 16 + lc] =
              fmaxf(acc[i][j][2 * jj], acc[i][j][2 * jj + 1]);
    __syncthreads();
    if (rt == 0) {
      const int row = t >> 2, chunk = (t & 3) * 32;
      unsigned short o[32];
      #pragma unroll
      for (int j2 = 0; j2 < 32; ++j2) o[j2] = f2bf(eps[row][chunk + j2] + bfp[chunk + j2]);
      unsigned short* dst = &fT[((size_t)(b * Q_ + (w0 >> 1) + row)) * C4 + chunk];
      #pragma unroll
      for (int u = 0; u < 4; ++u) *(uint4*)&dst[u * 8] = *(uint4*)&o[u * 8];
    } else {
      const int ch = t >> 1, half = (t & 1) * 32;
      const float bv = bhp[(rt - 2) * 128 + ch];
      unsigned short o[32];
      #pragma unroll
      for (int qq = 0; qq < 32; ++qq) o[qq] = f2bf(eps[half + qq][ch] + bv);
      unsigned short* dst = &h[((size_t)(b * C2 + (rt - 2) * 128 + ch)) * Q_ + (w0 >> 1) + half];
      #pragma unroll
      for (int u = 0; u < 4; ++u) *(uint4*)&dst[u * 8] = *(uint4*)&o[u * 8];
    }
  }
}

// ---------------------------------------------------------------------------
// K2 v5: staged GEMM identical to v4; NEW epilogue — per-chunk LDS transpose
// so beta^T rows are written as full 64B lines from single instructions.
// grid (Q/32, B), 1024 thr
// ---------------------------------------------------------------------------
__global__ __launch_bounds__(1024)
void k_attn(const unsigned short* __restrict__ fT, const unsigned short* __restrict__ gT,
            unsigned short* __restrict__ bT)
{
  const int b = blockIdx.y, q0 = blockIdx.x * 32;
  const int t = threadIdx.x, l = t & 63, wv = t >> 6;   // 16 waves
  const int qf = wv >> 3, kf = wv & 7;
  const int lcq = l & 15, lrq = l >> 4;

  __shared__ __align__(16) unsigned short Alds[32 * 128];       //  8 KB
  __shared__ __align__(16) unsigned short Blds[2][128 * 128];   // 64 KB
  __shared__ float redm[16][16];
  __shared__ float redl[16][16];

  // stage A once (linear): waves 0..7, rows 4w..4w+3
  if (wv < 8) {
    gload16(fT + ((size_t)(b * Q_ + q0 + wv * 4 + lrq)) * C4 + lcq * 8,
            Alds + wv * 512);
  }

  const unsigned short* Bbase = gT + (size_t)(b * W_) * C4;
  // stage B chunk nc into buf: dest linear; src col-granule pre-swizzled by row&15
  auto STAGEB = [&](int buf, int nc) {
    #pragma unroll
    for (int i = 0; i < 2; ++i) {
      const int row = i * 64 + wv * 4 + lrq;          // 0..127
      const int cg  = lcq ^ (row & 15);               // inverse swizzle on source
      gload16(Bbase + ((size_t)(nc * 128 + row)) * C4 + cg * 8,
              Blds[buf] + i * 8192 + wv * 512);
    }
  };

  STAGEB(0, 0);
  __syncthreads();     // drains A + B0

  // hoist A fragments (4 reads total; conflicts negligible)
  bf16x8 aT[4];
  #pragma unroll
  for (int kk = 0; kk < 4; ++kk)
    aT[kk] = *(const bf16x8*)&Alds[(qf * 16 + lcq) * 128 + kk * 32 + lrq * 8];

  f32x4 sacc[16];
  #pragma unroll
  for (int nc = 0; nc < 16; ++nc) sacc[nc] = (f32x4){0.f, 0.f, 0.f, 0.f};

  #pragma unroll
  for (int nc = 0; nc < 16; ++nc) {
    const int cur = nc & 1;
    if (nc) __syncthreads();              // drains stage of buf[cur]
    if (nc + 1 < 16) STAGEB(cur ^ 1, nc + 1);
    #pragma unroll
    for (int kk = 0; kk < 4; ++kk) {
      const bf16x8 bb = *(const bf16x8*)
          &Blds[cur][(kf * 16 + lcq) * 128 + ((kk * 4 + lrq) ^ lcq) * 8];
      sacc[nc] = MFMA(aT[kk], bb, sacc[nc]);
    }
  }

  // ---- softmax over k (per lane: 4 q's via reg r, 16 k's via nc) ----
  float mx[4], inv[4];
  #pragma unroll
  for (int r = 0; r < 4; ++r) {
    float m = sacc[0][r];
    #pragma unroll
    for (int nc = 1; nc < 16; ++nc) m = fmaxf(m, sacc[nc][r]);
    #pragma unroll
    for (int d = 1; d < 16; d <<= 1) m = fmaxf(m, __shfl_xor(m, d));
    mx[r] = m;
  }
  if (lcq == 0) {
    #pragma unroll
    for (int r = 0; r < 4; ++r) redm[wv][lrq * 4 + r] = mx[r];
  }
  __syncthreads();
  #pragma unroll
  for (int r = 0; r < 4; ++r) {
    float m = redm[qf * 8][lrq * 4 + r];
    #pragma unroll
    for (int w2 = 1; w2 < 8; ++w2) m = fmaxf(m, redm[qf * 8 + w2][lrq * 4 + r]);
    mx[r] = m;
  }
  #pragma unroll
  for (int r = 0; r < 4; ++r) {
    float s = 0.f;
    #pragma unroll
    for (int nc = 0; nc < 16; ++nc) {
      const float e = __expf(sacc[nc][r] - mx[r]);
      sacc[nc][r] = e;
      s += e;
    }
    #pragma unroll
    for (int d = 1; d < 16; d <<= 1) s += __shfl_xor(s, d);
    inv[r] = s;
  }
  if (lcq == 0) {
    #pragma unroll
    for (int r = 0; r < 4; ++r) redl[wv][lrq * 4 + r] = inv[r];
  }
  __syncthreads();
  #pragma unroll
  for (int r = 0; r < 4; ++r) {
    float s = redl[qf * 8][lrq * 4 + r];
    #pragma unroll
    for (int w2 = 1; w2 < 8; ++w2) s += redl[qf * 8 + w2][lrq * 4 + r];
    inv[r] = 1.f / s;
  }

  // ---- beta^T write via LDS transpose: full 64B lines per instruction ----
  // tb overlays Blds[0] (dead after GEMM loop): [128 k][34 q-pad] bf16
  unsigned short* tb = (unsigned short*)Blds;
  #pragma unroll
  for (int nc = 0; nc < 16; ++nc) {
    __syncthreads();                      // protect tb reuse (and redl phase)
    unsigned short o4[4];
    #pragma unroll
    for (int r = 0; r < 4; ++r) o4[r] = f2bf(sacc[nc][r] * inv[r]);
    // lane -> tb[kf*16+lcq][qf*16+lrq*4 .. +3]  (one 8B LDS write)
    *(uint2*)&tb[(kf * 16 + lcq) * 34 + qf * 16 + lrq * 4] = *(uint2*)o4;
    __syncthreads();
    // 1024 thr: row = t>>3 (128 rows), 8 lanes x 8B = one 64B line per row
    const int row = t >> 3, c8 = t & 7;
    *(uint2*)&bT[((size_t)(b * W_ + nc * 128 + row)) * Q_ + q0 + c8 * 4] =
        *(uint2*)&tb[row * 34 + c8 * 4];
  }
}

// ---------------------------------------------------------------------------
// K3: o1T = beta^T @ h^T, m97-style staged. Tile 128(k) x 128(c), BK=32.
// grid (16, 2, 16), 256 thr, 4 waves 2x2.
// ---------------------------------------------------------------------------
__global__ __launch_bounds__(256)
void k_o1(const unsigned short* __restrict__ bT, const unsigned short* __restrict__ h,
          unsigned short* __restrict__ o1T)
{
  const int b = blockIdx.z, n0 = blockIdx.y * 128, m0 = blockIdx.x * 128;
  const int t = threadIdx.x, l = t & 63, wv = t >> 6;
  const int wr = wv >> 1, wc = wv & 1;

  __shared__ __align__(16) char smraw[34816];   // staging 32KB | epilogue 128x136 bf16
  unsigned short* stg = (unsigned short*)smraw;
  unsigned short (*ot)[136] = (unsigned short(*)[136])smraw;

  const unsigned short* Abase = bT + (size_t)(b * W_ + m0) * Q_;
  const unsigned short* Bbase = h + (size_t)(b * C2 + n0) * Q_;

  const int wub = (t & 192) * 8;
  const int r0s = t >> 2, kcs = (t & 3) * 8;

  auto STAGE = [&](int buf, int q0) {
    #pragma unroll
    for (int i = 0; i < 2; ++i) {
      const int row = i * 64 + r0s;
      gload16(Abase + (size_t)row * Q_ + q0 + kcs, stg + (buf * 2 + 0) * 4096 + i * 2048 + wub);
      gload16(Bbase + (size_t)row * Q_ + q0 + kcs, stg + (buf * 2 + 1) * 4096 + i * 2048 + wub);
    }
  };

  f32x4 acc[4][4];
  #pragma unroll
  for (int i = 0; i < 4; ++i)
    #pragma unroll
    for (int j = 0; j < 4; ++j) acc[i][j] = (f32x4){0.f, 0.f, 0.f, 0.f};

  STAGE(0, 0);
  for (int kt = 0; kt < 32; ++kt) {
    const int cur = kt & 1;
    __syncthreads();
    if (kt + 1 < 32) STAGE(cur ^ 1, (kt + 1) * 32);
    const unsigned short* As = stg + (cur * 2 + 0) * 4096;
    const unsigned short* Bs = stg + (cur * 2 + 1) * 4096;
    bf16x8 a[4], bb[4];
    #pragma unroll
    for (int i = 0; i < 4; ++i)
      a[i] = *(const bf16x8*)&As[(wr * 64 + i * 16 + (l & 15)) * 32 + ((l >> 4) << 3)];
    #pragma unroll
    for (int j = 0; j < 4; ++j)
      bb[j] = *(const bf16x8*)&Bs[(wc * 64 + j * 16 + (l & 15)) * 32 + ((l >> 4) << 3)];
    #pragma unroll
    for (int i = 0; i < 4; ++i)
      #pragma unroll
      for (int j = 0; j < 4; ++j)
        acc[i][j] = MFMA(a[i], bb[j], acc[i][j]);
  }
  __syncthreads();

  const int lr = l >> 4, lc = l & 15;
  #pragma unroll
  for (int i = 0; i < 4; ++i)
    #pragma unroll
    for (int j = 0; j < 4; ++j)
      #pragma unroll
      for (int r = 0; r < 4; ++r)
        ot[wr * 64 + i * 16 + lr * 4 + r][wc * 64 + j * 16 + lc] = f2bf(acc[i][j][r]);
  __syncthreads();
  const int row = t >> 1, half = (t & 1) * 64;
  unsigned short* dst = &o1T[((size_t)(b * W_ + m0 + row)) * C2 + n0 + half];
  #pragma unroll
  for (int u = 0; u < 8; ++u)
    *(uint4*)&dst[u * 8] = *(uint4*)&ot[row][half + u * 8];
}

// ---------------------------------------------------------------------------
// K4: out = gamma*(o1T @ wa^T + ba) + x. (unchanged)
// ---------------------------------------------------------------------------
__global__ __launch_bounds__(256)
void k_out(const unsigned short* __restrict__ o1T, const unsigned short* __restrict__ wabf,
           const float* __restrict__ ba, const float* __restrict__ x,
           const float* __restrict__ gamma, float* __restrict__ out)
{
  const int b = blockIdx.z, co0 = blockIdx.y * 128, w0 = blockIdx.x * 128;
  const int t = threadIdx.x, l = t & 63, wv = t >> 6;
  const int wr = wv >> 1, wc = wv & 1;

  const unsigned short* A  = o1T + (size_t)(b * W_ + w0 + wr * 64) * C2;
  const unsigned short* Bt = wabf + (size_t)(co0 + wc * 64) * C2;

  f32x4 acc[4][4];
  #pragma unroll
  for (int i = 0; i < 4; ++i)
    #pragma unroll
    for (int j = 0; j < 4; ++j) acc[i][j] = (f32x4){0.f, 0.f, 0.f, 0.f};

  for (int c0 = 0; c0 < C2; c0 += 32) {
    bf16x8 a[4], bb[4];
    #pragma unroll
    for (int i = 0; i < 4; ++i) a[i]  = ldfrag(A  + (size_t)(i * 16) * C2 + c0, C2);
    #pragma unroll
    for (int j = 0; j < 4; ++j) bb[j] = ldfrag(Bt + (size_t)(j * 16) * C2 + c0, C2);
    #pragma unroll
    for (int i = 0; i < 4; ++i)
      #pragma unroll
      for (int j = 0; j < 4; ++j)
        acc[i][j] = MFMA(a[i], bb[j], acc[i][j]);
  }

  const float gm = gamma[0];
  const int lr = l >> 4, lc = l & 15;
  #pragma unroll
  for (int i = 0; i < 4; ++i)
    #pragma unroll
    for (int j = 0; j < 4; ++j) {
      const int co = co0 + wc * 64 + j * 16 + lc;
      const int w  = w0 + wr * 64 + i * 16 + lr * 4;
      const float bb2 = ba[co];
      const size_t idx = ((size_t)(b * C_ + co)) * W_ + w;
      const float4 xv = *(const float4*)&x[idx];
      float4 ov;
      ov.x = gm * (acc[i][j][0] + bb2) + xv.x;
      ov.y = gm * (acc[i][j][1] + bb2) + xv.y;
      ov.z = gm * (acc[i][j][2] + bb2) + xv.z;
      ov.w = gm * (acc[i][j][3] + bb2) + xv.w;
      *(float4*)&out[idx] = ov;
    }
}

// ---------------------------------------------------------------------------
extern "C" void kernel_launch(void* const* d_in, const int* in_sizes, int n_in,
                              void* d_out, int out_size, void* d_ws, size_t ws_size,
                              hipStream_t stream)
{
  const float* x     = (const float*)d_in[0];
  const float* wf    = (const float*)d_in[1];
  const float* bfp   = (const float*)d_in[2];
  const float* wg    = (const float*)d_in[3];
  const float* bgp   = (const float*)d_in[4];
  const float* wh    = (const float*)d_in[5];
  const float* bhp   = (const float*)d_in[6];
  const float* wa    = (const float*)d_in[7];
  const float* ba    = (const float*)d_in[8];
  const float* gamma = (const float*)d_in[9];
  float* out = (float*)d_out;

  unsigned short* ws = (unsigned short*)d_ws;
  size_t off = 0;
  unsigned short* wbf = ws + off;  off += 393216;
  unsigned short* xT  = ws + off;  off += (size_t)B_ * W_ * C_;
  unsigned short* fT  = ws + off;  off += (size_t)B_ * Q_ * C4;
  unsigned short* gT  = ws + off;  off += (size_t)B_ * W_ * C4;
  unsigned short* h   = ws + off;  off += (size_t)B_ * C2 * Q_;
  unsigned short* bT  = ws + off;  off += (size_t)B_ * W_ * Q_;
  unsigned short* o1T = ws + off;  off += (size_t)B_ * W_ * C2;
  unsigned short* wabf = wbf + 262144;

  k_cvt<<<dim3(1536), dim3(256), 0, stream>>>(wf, wg, wh, wa, wbf);
  k_tx<<<dim3(W_ / 64, C_ / 64, B_), dim3(256), 0, stream>>>(x, xT);
  k_fgh<<<dim3(W_ / 128, 4, B_), dim3(256), 0, stream>>>(xT, wbf, bfp, bgp, bhp, fT, gT, h);
  k_attn<<<dim3(Q_ / 32, B_), dim3(1024), 0, stream>>>(fT, gT, bT);
  k_o1<<<dim3(W_ / 128, 2, B_), dim3(256), 0, stream>>>(bT, h, o1T);
  k_out<<<dim3(W_ / 128, 4, B_), dim3(256), 0, stream>>>(o1T, wabf, ba, x, gamma, out);
}